// Round 12
// baseline (370.634 us; speedup 1.0000x reference)
//
#include <hip/hip_runtime.h>
#include <hip/hip_bf16.h>
#include <cstdint>
#include <math.h>

typedef __attribute__((ext_vector_type(8))) __bf16 bfx8;
typedef __attribute__((ext_vector_type(4))) __bf16 bfx4;
typedef __attribute__((ext_vector_type(4))) float f32x4;

#define EPSN 1e-8f
// 5.0 / ln(2) -> softmax uses exp2
#define SM_SCALE 7.2134752044448170f

__device__ __forceinline__ void gload_lds16(const void* g, void* l) {
    __builtin_amdgcn_global_load_lds(
        (__attribute__((address_space(1))) void*)g,
        (__attribute__((address_space(3))) void*)l,
        16, 0, 0);
}

// ------------- query norm + bf16 cast + embedding copy + row norms -------------
__global__ __launch_bounds__(256) void qnorm_kernel(
    const float* __restrict__ q, __bf16* __restrict__ qbf,
    float* __restrict__ emb, float* __restrict__ qn, int D) {
    const int tid = threadIdx.x;
    const size_t roff = (size_t)blockIdx.x * D;
    const float4* qr = (const float4*)(q + roff);
    float4* er = (float4*)(emb + roff);
    const int PASS = D >> 10;
    float4 v[4];
    float ss = 0.f;
    for (int p = 0; p < PASS; ++p) {
        v[p] = qr[p * 256 + tid];
        ss += v[p].x * v[p].x + v[p].y * v[p].y + v[p].z * v[p].z + v[p].w * v[p].w;
    }
    for (int o = 32; o; o >>= 1) ss += __shfl_xor(ss, o);
    __shared__ float sred[4];
    if ((tid & 63) == 0) sred[tid >> 6] = ss;
    __syncthreads();
    float tot = sred[0] + sred[1] + sred[2] + sred[3];
    float nrm = fmaxf(sqrtf(tot), EPSN);
    float inv = 1.f / nrm;
    if (tid == 0) qn[blockIdx.x] = nrm;
    for (int p = 0; p < PASS; ++p) {
        er[p * 256 + tid] = v[p];
        bfx4 o4 = {(__bf16)(v[p].x * inv), (__bf16)(v[p].y * inv),
                   (__bf16)(v[p].z * inv), (__bf16)(v[p].w * inv)};
        *(bfx4*)(qbf + roff + (size_t)(p * 256 + tid) * 4) = o4;
    }
}

// --- prototype norm + cast, raw-P cast, fc_w cast, zero pad rows, zero PWf ---
__global__ __launch_bounds__(256) void pnorm_kernel(
    const float* __restrict__ P, const float* __restrict__ W,
    __bf16* __restrict__ Pn, __bf16* __restrict__ Wb, __bf16* __restrict__ Pr,
    float* __restrict__ PWf, int C, int D, int CP) {
    const int c = blockIdx.x;
    const int tid = threadIdx.x;
    const int PASS = D >> 10;
    // zero this block's PWf row (CP floats, 4/thread)
    {
        float4 z4 = {0.f, 0.f, 0.f, 0.f};
        *(float4*)(PWf + (size_t)c * CP + tid * 4) = z4;
    }
    if (c >= C) {
        bfx4 z = {(__bf16)0.f, (__bf16)0.f, (__bf16)0.f, (__bf16)0.f};
        for (int p = 0; p < PASS; ++p) {
            size_t e = (size_t)c * D + (size_t)(p * 256 + tid) * 4;
            *(bfx4*)(Pn + e) = z;
            *(bfx4*)(Wb + e) = z;
            *(bfx4*)(Pr + e) = z;
        }
        return;
    }
    const float4* pr = (const float4*)(P + (size_t)c * D);
    float4 v[4];
    float ss = 0.f;
    for (int p = 0; p < PASS; ++p) {
        v[p] = pr[p * 256 + tid];
        ss += v[p].x * v[p].x + v[p].y * v[p].y + v[p].z * v[p].z + v[p].w * v[p].w;
    }
    for (int o = 32; o; o >>= 1) ss += __shfl_xor(ss, o);
    __shared__ float sred[4];
    if ((tid & 63) == 0) sred[tid >> 6] = ss;
    __syncthreads();
    float tot = sred[0] + sred[1] + sred[2] + sred[3];
    float inv = 1.f / fmaxf(sqrtf(tot), EPSN);
    const float4* wr_ = (const float4*)(W + (size_t)c * D);
    for (int p = 0; p < PASS; ++p) {
        size_t e = (size_t)c * D + (size_t)(p * 256 + tid) * 4;
        bfx4 o4 = {(__bf16)(v[p].x * inv), (__bf16)(v[p].y * inv),
                   (__bf16)(v[p].z * inv), (__bf16)(v[p].w * inv)};
        *(bfx4*)(Pn + e) = o4;
        bfx4 r4 = {(__bf16)v[p].x, (__bf16)v[p].y, (__bf16)v[p].z, (__bf16)v[p].w};
        *(bfx4*)(Pr + e) = r4;
        float4 wv = wr_[p * 256 + tid];
        bfx4 w4 = {(__bf16)wv.x, (__bf16)wv.y, (__bf16)wv.z, (__bf16)wv.w};
        *(bfx4*)(Wb + e) = w4;
    }
}

// ---------------- f32 -> bf16 cast (8 elems/thread) ----------------
__global__ __launch_bounds__(256) void cast_kernel(
    const float* __restrict__ src, __bf16* __restrict__ dst) {
    const size_t i = ((size_t)blockIdx.x * 256 + threadIdx.x) * 8;
    float4 a = *(const float4*)(src + i);
    float4 b = *(const float4*)(src + i + 4);
    bfx8 o = {(__bf16)a.x, (__bf16)a.y, (__bf16)a.z, (__bf16)a.w,
              (__bf16)b.x, (__bf16)b.y, (__bf16)b.z, (__bf16)b.w};
    *(bfx8*)(dst + i) = o;
}

// ------------- PW^T split-K GEMM: out[c2,c1] += sum_d A[c2,d]*B[c1,d] -------------
__global__ __launch_bounds__(256) void pwt_gemm(
    const __bf16* __restrict__ A, const __bf16* __restrict__ B,
    int Ktot, int KSPL, float* __restrict__ out, int ldo) {
    __shared__ __bf16 As[128 * 32];
    __shared__ __bf16 Bs[128 * 32];
    const int tid = threadIdx.x;
    const int lane = tid & 63, wid = tid >> 6;
    const int wr = wid >> 1, wc = wid & 1;
    const int fr = lane & 15, fq = lane >> 4;
    const int m0 = blockIdx.y * 128, n0 = blockIdx.x * 128;
    const int k0 = blockIdx.z * KSPL;

    const int flat0 = tid * 16;
    const int r0 = flat0 >> 6, c0e = (flat0 & 63) >> 1;
    const int flat1 = flat0 + 4096;
    const int r1 = flat1 >> 6, c1e = (flat1 & 63) >> 1;

    f32x4 acc[4][4] = {};

    for (int kt = k0; kt < k0 + KSPL; kt += 32) {
        __syncthreads();
        gload_lds16(A + (size_t)(m0 + r0) * Ktot + kt + c0e, (char*)As + flat0);
        gload_lds16(A + (size_t)(m0 + r1) * Ktot + kt + c1e, (char*)As + flat1);
        gload_lds16(B + (size_t)(n0 + r0) * Ktot + kt + c0e, (char*)Bs + flat0);
        gload_lds16(B + (size_t)(n0 + r1) * Ktot + kt + c1e, (char*)Bs + flat1);
        asm volatile("s_waitcnt vmcnt(0)" ::: "memory");
        __syncthreads();
        bfx8 af[4], bfv[4];
#pragma unroll
        for (int m = 0; m < 4; ++m)
            af[m] = *(const bfx8*)(As + (wr * 64 + m * 16 + fr) * 32 + fq * 8);
#pragma unroll
        for (int n = 0; n < 4; ++n)
            bfv[n] = *(const bfx8*)(Bs + (wc * 64 + n * 16 + fr) * 32 + fq * 8);
#pragma unroll
        for (int m = 0; m < 4; ++m)
#pragma unroll
            for (int n = 0; n < 4; ++n)
                acc[m][n] = __builtin_amdgcn_mfma_f32_16x16x32_bf16(
                    af[m], bfv[n], acc[m][n], 0, 0, 0);
    }
#pragma unroll
    for (int m = 0; m < 4; ++m) {
        const int grb = m0 + wr * 64 + m * 16 + fq * 4;
#pragma unroll
        for (int n = 0; n < 4; ++n) {
            const int gc = n0 + wc * 64 + n * 16 + fr;
#pragma unroll
            for (int j = 0; j < 4; ++j)
                atomicAdd(out + (size_t)(grb + j) * ldo + gc, acc[m][n][j]);
        }
    }
}

// ---------------- row softmax over C (ld CP), in place ----------------
__global__ __launch_bounds__(256) void softmax_kernel(
    __bf16* __restrict__ S, int C, int CP) {
    const int tid = threadIdx.x;
    __bf16* row = S + (size_t)blockIdx.x * CP;
    bfx4 v4 = *(const bfx4*)(row + tid * 4);
    const int base = tid * 4;
    float v[4];
    float mx = -INFINITY, rs = 0.f;
#pragma unroll
    for (int j = 0; j < 4; ++j) {
        v[j] = (float)v4[j];
        if (base + j < C) { mx = fmaxf(mx, v[j]); rs += v[j]; }
    }
    for (int o = 32; o; o >>= 1) {
        mx = fmaxf(mx, __shfl_xor(mx, o));
        rs += __shfl_xor(rs, o);
    }
    __shared__ float smx[4], srs[4], sps[4];
    if ((tid & 63) == 0) { smx[tid >> 6] = mx; srs[tid >> 6] = rs; }
    __syncthreads();
    mx = fmaxf(fmaxf(smx[0], smx[1]), fmaxf(smx[2], smx[3]));
    rs = srs[0] + srs[1] + srs[2] + srs[3];
    float p[4], ps = 0.f;
#pragma unroll
    for (int j = 0; j < 4; ++j) {
        p[j] = (base + j < C) ? exp2f((v[j] - mx) * SM_SCALE) : 0.f;
        ps += p[j];
    }
    for (int o = 32; o; o >>= 1) ps += __shfl_xor(ps, o);
    if ((tid & 63) == 0) sps[tid >> 6] = ps;
    __syncthreads();
    ps = sps[0] + sps[1] + sps[2] + sps[3];
    float inv = (rs != 0.f) ? 1.f / ps : 0.f;  // reference's nonzero mask
    bfx4 o4 = {(__bf16)(p[0] * inv), (__bf16)(p[1] * inv),
               (__bf16)(p[2] * inv), (__bf16)(p[3] * inv)};
    *(bfx4*)(row + tid * 4) = o4;
}

// ================= 256x256 8-phase NT bf16 GEMM (BK=64, 8 waves) =================
// TEMPLATE-EXACT schedule (round-9/11, best measured).  Core loop unchanged.
// MODE 4: bn0 < cpEl: B-op=B_ (Pn), out bf16 Scos; else B-op=B2 (Wb), qW part:
//   useqw ? QWb[gr*cpEl+c] = bf16(auxA[gr]*acc + auxB[c])
//         : logits[gr*nv+c] = auxA[gr]*acc + auxB[c]     (c = gc-cpEl < nv)
// MODE 5: useqw ? logits = acc + (float)QWb[gr*cpEl+gc] : logits += acc.
template <int MODE>
__global__ __launch_bounds__(512, 2) void gemm8p(
    const __bf16* __restrict__ A, const __bf16* __restrict__ B_,
    const __bf16* __restrict__ B2,
    int K, int NT, int nbxl, int nwg,
    void* __restrict__ outA, float* __restrict__ outB,
    const float* __restrict__ auxA, const float* __restrict__ auxB,
    __bf16* __restrict__ qwbuf, int useqw,
    int cpEl, int nv) {
    __shared__ __bf16 lds[65536];  // 128 KiB

    const int tid = threadIdx.x;
    const int lane = tid & 63, wid = tid >> 6;
    const int wr = wid >> 2, wc = wid & 3;
    const int fr = lane & 15, fq = lane >> 4;
    const int wr4 = wr * 4, wc2 = wc * 2;
    const int frs = fr * 32 + ((fq * 8) ^ ((fr & 8) << 1));

    // XCD-aware bijective block swizzle (nwg % 8 == 0)
    const int nbx = 1 << nbxl;
    const int lin = blockIdx.y * nbx + blockIdx.x;
    const int swz = (lin & 7) * (nwg >> 3) + (lin >> 3);
    const int bm0 = (swz >> nbxl) * 256;
    const int bn0 = (swz & (nbx - 1)) * 256;

    // staging source mapping (inverse swizzle)
    int row0, col0, row1, col1;
    {
        int Le = tid * 8;
        int st = Le >> 9, w = Le & 511;
        row0 = (st >> 1) * 16 + (w >> 5);
        col0 = (st & 1) * 32 + ((w & 31) ^ ((w >> 4) & 16));
        Le = tid * 8 + 4096;
        st = Le >> 9; w = Le & 511;
        row1 = (st >> 1) * 16 + (w >> 5);
        col1 = (st & 1) * 32 + ((w & 31) ^ ((w >> 4) & 16));
    }
    const __bf16* Ap = A + (size_t)bm0 * K;
    const __bf16* Bbase = B_;
    int bnloc = bn0;
    if (MODE == 4 && bn0 >= cpEl) { Bbase = B2; bnloc = bn0 - cpEl; }
    const __bf16* Bp = Bbase + (size_t)bnloc * K;
    const size_t hstride = (size_t)128 * K;
    const __bf16* srcA0 = Ap + (size_t)row0 * K + col0;
    const __bf16* srcA1 = Ap + (size_t)row1 * K + col1;
    const __bf16* srcB0 = Bp + (size_t)row0 * K + col0;
    const __bf16* srcB1 = Bp + (size_t)row1 * K + col1;
    const int ldsoff = tid * 8;

    // H: 0=A-h0, 1=B-h0, 2=A-h1, 3=B-h1 (compile-time); t runtime
#define STG(H, t) do {                                                         \
    const int kt_ = (t) << 6;                                                  \
    __bf16* d_ = lds + ((((t) & 1) << 14) + (((H) >> 1) << 13) +               \
                        (((H) & 1) ? 32768 : 0)) + ldsoff;                     \
    const __bf16* s0_ = (((H) & 1) ? srcB0 : srcA0) +                          \
                        (((H) >> 1) ? hstride : 0) + kt_;                      \
    const __bf16* s1_ = (((H) & 1) ? srcB1 : srcA1) +                          \
                        (((H) >> 1) ? hstride : 0) + kt_;                      \
    gload_lds16(s0_, d_);                                                      \
    gload_lds16(s1_, d_ + 4096);                                               \
} while (0)

    bfx8 fA0[4][2], fA1[4][2], fB0[2][2], fB1[2][2];
    f32x4 acc[4][4][2] = {};

#define RDA(F, H, BUFE) do {                                                   \
    _Pragma("unroll") for (int m_ = 0; m_ < 4; ++m_)                           \
      _Pragma("unroll") for (int ks_ = 0; ks_ < 2; ++ks_)                      \
        F[m_][ks_] = *(const bfx8*)&lds[(BUFE) +                               \
            (((((H) * 8) + wr4 + m_) * 2 + ks_) << 9) + frs];                  \
} while (0)
#define RDB(F, H, BUFE) do {                                                   \
    _Pragma("unroll") for (int n_ = 0; n_ < 2; ++n_)                           \
      _Pragma("unroll") for (int ks_ = 0; ks_ < 2; ++ks_)                      \
        F[n_][ks_] = *(const bfx8*)&lds[32768 + (BUFE) +                       \
            (((((H) * 8) + wc2 + n_) * 2 + ks_) << 9) + frs];                  \
} while (0)
#define MM(QI, FA, FB) do {                                                    \
    __builtin_amdgcn_s_setprio(1);                                             \
    _Pragma("unroll") for (int ks_ = 0; ks_ < 2; ++ks_)                        \
      _Pragma("unroll") for (int m_ = 0; m_ < 4; ++m_)                         \
        _Pragma("unroll") for (int n_ = 0; n_ < 2; ++n_)                       \
          acc[QI][m_][n_] = __builtin_amdgcn_mfma_f32_16x16x32_bf16(           \
              FA[m_][ks_], FB[n_][ks_], acc[QI][m_][n_], 0, 0, 0);             \
    __builtin_amdgcn_s_setprio(0);                                             \
} while (0)
#define BAR __builtin_amdgcn_s_barrier()
#define LGKM(N) asm volatile("s_waitcnt lgkmcnt(" #N ")" ::: "memory")
#define VMC(N) asm volatile("s_waitcnt vmcnt(" #N ")" ::: "memory")

    // prologue: tile0 {Ah0,Bh0,Ah1,Bh1} + tile1 {Ah0,Bh0,Ah1} = 14 loads
    STG(0, 0); STG(1, 0); STG(2, 0); STG(3, 0);
    STG(0, 1); STG(1, 1); STG(2, 1);
    VMC(6);
    BAR;

    for (int T = 0; T <= NT - 3; ++T) {
        const int bufe = (T & 1) << 14;
        // ph0: read Ah0,Bh0(T); stage Bh1(T+1)
        RDA(fA0, 0, bufe); RDB(fB0, 0, bufe); STG(3, T + 1); LGKM(8); BAR; LGKM(0);
        MM(0, fA0, fB0); BAR;
        // ph1: read Bh1(T); stage Ah0(T+2)
        RDB(fB1, 1, bufe); STG(0, T + 2); BAR; LGKM(0);
        MM(1, fA0, fB1); BAR;
        // ph2: read Ah1(T); stage Bh0(T+2)
        RDA(fA1, 1, bufe); STG(1, T + 2); BAR; LGKM(0);
        MM(3, fA1, fB1); BAR;
        // ph3: stage Ah1(T+2)
        STG(2, T + 2); BAR;
        MM(2, fA1, fB0); VMC(6); BAR;
    }
    {   // T = NT-2: stage only Bh1(NT-1); full drain at ph3
        const int T = NT - 2;
        const int bufe = (T & 1) << 14;
        RDA(fA0, 0, bufe); RDB(fB0, 0, bufe); STG(3, T + 1); LGKM(8); BAR; LGKM(0);
        MM(0, fA0, fB0); BAR;
        RDB(fB1, 1, bufe); BAR; LGKM(0);
        MM(1, fA0, fB1); BAR;
        RDA(fA1, 1, bufe); BAR; LGKM(0);
        MM(3, fA1, fB1); BAR;
        BAR;
        MM(2, fA1, fB0); VMC(0); BAR;
    }
    {   // T = NT-1: no stages, no vmcnt
        const int bufe = ((NT - 1) & 1) << 14;
        RDA(fA0, 0, bufe); RDB(fB0, 0, bufe); LGKM(8); BAR; LGKM(0);
        MM(0, fA0, fB0); BAR;
        RDB(fB1, 1, bufe); BAR; LGKM(0);
        MM(1, fA0, fB1); BAR;
        RDA(fA1, 1, bufe); BAR; LGKM(0);
        MM(3, fA1, fB1); BAR;
        MM(2, fA1, fB0);
    }
#undef STG
#undef RDA
#undef RDB
#undef MM
#undef BAR
#undef LGKM
#undef VMC

    // epilogue
#pragma unroll
    for (int q = 0; q < 4; ++q) {
        const int qm_ = q >> 1, qn_ = q & 1;
#pragma unroll
        for (int m = 0; m < 4; ++m) {
            const int grb = bm0 + qm_ * 128 + wr * 64 + m * 16 + fq * 4;
#pragma unroll
            for (int n = 0; n < 2; ++n) {
                const int gc = bn0 + qn_ * 128 + wc * 32 + n * 16 + fr;
#pragma unroll
                for (int j = 0; j < 4; ++j) {
                    const int gr = grb + j;
                    const float va = acc[q][m][n][j];
                    if (MODE == 4) {
                        if (bn0 < cpEl) {
                            ((__bf16*)outA)[(size_t)gr * cpEl + gc] = (__bf16)va;
                        } else {
                            const int c = gc - cpEl;
                            if (c < nv) {
                                const float val = auxA[gr] * va + auxB[c];
                                if (useqw)
                                    qwbuf[(size_t)gr * cpEl + c] = (__bf16)val;
                                else
                                    outB[(size_t)gr * nv + c] = val;
                            }
                        }
                    } else {  // MODE 5
                        if (gc < nv) {
                            if (useqw) {
                                outB[(size_t)gr * nv + gc] =
                                    va + (float)qwbuf[(size_t)gr * cpEl + gc];
                            } else {
                                float* p = outB + (size_t)gr * nv + gc;
                                *p = *p + va;
                            }
                        }
                    }
                }
            }
        }
    }
}

extern "C" void kernel_launch(void* const* d_in, const int* in_sizes, int n_in,
                              void* d_out, int out_size, void* d_ws, size_t ws_size,
                              hipStream_t stream) {
    const float* q  = (const float*)d_in[0];
    const float* pr = (const float*)d_in[1];
    const float* fw = (const float*)d_in[2];
    const float* fb = (const float*)d_in[3];
    const int C = in_sizes[3];              // 1000
    const int D = in_sizes[1] / C;          // 2048
    const int B = in_sizes[0] / D;          // 16384
    const int CP = (C + 127) & ~127;        // 1024

    float* logits = (float*)d_out;          // [B, C] f32
    float* emb = logits + (size_t)B * C;    // [B, D] f32

    char* w = (char*)d_ws;
    __bf16* Qb  = (__bf16*)w; w += (size_t)B * D * 2;     // 67.1 MB
    __bf16* Pn  = (__bf16*)w; w += (size_t)CP * D * 2;    // 4.2 MB
    __bf16* Wb  = (__bf16*)w; w += (size_t)CP * D * 2;    // 4.2 MB
    __bf16* PWT = (__bf16*)w; w += (size_t)CP * CP * 2;   // 2.1 MB
    float*  qn  = (float*)w;  w += (size_t)B * 4;         // 64 KB
    __bf16* Scos = (__bf16*)w; w += (size_t)B * CP * 2;   // 33.6 MB
    __bf16* QWb = (__bf16*)w; w += (size_t)B * CP * 2;    // 33.6 MB (optional)
    const int useqw = ((size_t)(w - (char*)d_ws) <= ws_size) ? 1 : 0;
    // transient aliases inside Scos (dead before bigGEMM writes Scos):
    float*  PWf = (float*)Scos;                           // CP*CP f32 = 4.2 MB
    __bf16* Pr  = Scos + (size_t)4 * 1024 * 1024;         // 4.2 MB, at +8 MB

    qnorm_kernel<<<B, 256, 0, stream>>>(q, Qb, emb, qn, D);
    pnorm_kernel<<<CP, 256, 0, stream>>>(pr, fw, Pn, Wb, Pr, PWf, C, D, CP);

    // PW^T = Wb @ Pr^T  (split-K=4, atomic f32), then cast to bf16
    pwt_gemm<<<dim3(CP / 128, CP / 128, 4), 256, 0, stream>>>(
        Wb, Pr, D, D / 4, PWf, CP);
    cast_kernel<<<(CP * CP) / 2048, 256, 0, stream>>>(PWf, PWT);

    // fused: Scos = Qb@Pn^T (bf16) | qW part -> QWb bf16 (or logits f32)
    {
        const int nbx = 2 * CP / 256, nby = B / 256;  // 8 x 64 = 512
        gemm8p<4><<<dim3(nbx, nby), 512, 0, stream>>>(
            Qb, Pn, Wb, D, D / 64, 3, nbx * nby,
            (void*)Scos, logits, qn, fb, QWb, useqw, CP, C);
    }
    softmax_kernel<<<B, 256, 0, stream>>>(Scos, C, CP);
    // logits = attn @ PWT + QWb   (K = CP)
    {
        const int nbx = CP / 256, nby = B / 256;  // 4 x 64 = 256
        gemm8p<5><<<dim3(nbx, nby), 512, 0, stream>>>(
            Scos, PWT, nullptr, CP, CP / 64, 2, nbx * nby,
            nullptr, logits, nullptr, nullptr, QWb, useqw, CP, C);
    }
}

// Round 13
// 340.780 us; speedup vs baseline: 1.0876x; 1.0876x over previous
//
#include <hip/hip_runtime.h>
#include <hip/hip_bf16.h>
#include <cstdint>
#include <math.h>

typedef __attribute__((ext_vector_type(8))) __bf16 bfx8;
typedef __attribute__((ext_vector_type(4))) __bf16 bfx4;
typedef __attribute__((ext_vector_type(4))) float f32x4;

#define EPSN 1e-8f
// 5.0 / ln(2) -> softmax uses exp2
#define SM_SCALE 7.2134752044448170f

__device__ __forceinline__ void gload_lds16(const void* g, void* l) {
    __builtin_amdgcn_global_load_lds(
        (__attribute__((address_space(1))) void*)g,
        (__attribute__((address_space(3))) void*)l,
        16, 0, 0);
}

// ------------- query norm + bf16 cast + embedding copy + row norms -------------
__global__ __launch_bounds__(256) void qnorm_kernel(
    const float* __restrict__ q, __bf16* __restrict__ qbf,
    float* __restrict__ emb, float* __restrict__ qn, int D) {
    const int tid = threadIdx.x;
    const size_t roff = (size_t)blockIdx.x * D;
    const float4* qr = (const float4*)(q + roff);
    float4* er = (float4*)(emb + roff);
    const int PASS = D >> 10;
    float4 v[4];
    float ss = 0.f;
    for (int p = 0; p < PASS; ++p) {
        v[p] = qr[p * 256 + tid];
        ss += v[p].x * v[p].x + v[p].y * v[p].y + v[p].z * v[p].z + v[p].w * v[p].w;
    }
    for (int o = 32; o; o >>= 1) ss += __shfl_xor(ss, o);
    __shared__ float sred[4];
    if ((tid & 63) == 0) sred[tid >> 6] = ss;
    __syncthreads();
    float tot = sred[0] + sred[1] + sred[2] + sred[3];
    float nrm = fmaxf(sqrtf(tot), EPSN);
    float inv = 1.f / nrm;
    if (tid == 0) qn[blockIdx.x] = nrm;
    for (int p = 0; p < PASS; ++p) {
        er[p * 256 + tid] = v[p];
        bfx4 o4 = {(__bf16)(v[p].x * inv), (__bf16)(v[p].y * inv),
                   (__bf16)(v[p].z * inv), (__bf16)(v[p].w * inv)};
        *(bfx4*)(qbf + roff + (size_t)(p * 256 + tid) * 4) = o4;
    }
}

// --- prototype norm + cast, raw-P cast, fc_w cast, zero pad rows, zero PWf ---
__global__ __launch_bounds__(256) void pnorm_kernel(
    const float* __restrict__ P, const float* __restrict__ W,
    __bf16* __restrict__ Pn, __bf16* __restrict__ Wb, __bf16* __restrict__ Pr,
    float* __restrict__ PWf, int C, int D, int CP) {
    const int c = blockIdx.x;
    const int tid = threadIdx.x;
    const int PASS = D >> 10;
    // zero this block's PWf row (CP floats, 4/thread)
    {
        float4 z4 = {0.f, 0.f, 0.f, 0.f};
        *(float4*)(PWf + (size_t)c * CP + tid * 4) = z4;
    }
    if (c >= C) {
        bfx4 z = {(__bf16)0.f, (__bf16)0.f, (__bf16)0.f, (__bf16)0.f};
        for (int p = 0; p < PASS; ++p) {
            size_t e = (size_t)c * D + (size_t)(p * 256 + tid) * 4;
            *(bfx4*)(Pn + e) = z;
            *(bfx4*)(Wb + e) = z;
            *(bfx4*)(Pr + e) = z;
        }
        return;
    }
    const float4* pr = (const float4*)(P + (size_t)c * D);
    float4 v[4];
    float ss = 0.f;
    for (int p = 0; p < PASS; ++p) {
        v[p] = pr[p * 256 + tid];
        ss += v[p].x * v[p].x + v[p].y * v[p].y + v[p].z * v[p].z + v[p].w * v[p].w;
    }
    for (int o = 32; o; o >>= 1) ss += __shfl_xor(ss, o);
    __shared__ float sred[4];
    if ((tid & 63) == 0) sred[tid >> 6] = ss;
    __syncthreads();
    float tot = sred[0] + sred[1] + sred[2] + sred[3];
    float inv = 1.f / fmaxf(sqrtf(tot), EPSN);
    const float4* wr_ = (const float4*)(W + (size_t)c * D);
    for (int p = 0; p < PASS; ++p) {
        size_t e = (size_t)c * D + (size_t)(p * 256 + tid) * 4;
        bfx4 o4 = {(__bf16)(v[p].x * inv), (__bf16)(v[p].y * inv),
                   (__bf16)(v[p].z * inv), (__bf16)(v[p].w * inv)};
        *(bfx4*)(Pn + e) = o4;
        bfx4 r4 = {(__bf16)v[p].x, (__bf16)v[p].y, (__bf16)v[p].z, (__bf16)v[p].w};
        *(bfx4*)(Pr + e) = r4;
        float4 wv = wr_[p * 256 + tid];
        bfx4 w4 = {(__bf16)wv.x, (__bf16)wv.y, (__bf16)wv.z, (__bf16)wv.w};
        *(bfx4*)(Wb + e) = w4;
    }
}

// ---------------- f32 -> bf16 cast (8 elems/thread) ----------------
__global__ __launch_bounds__(256) void cast_kernel(
    const float* __restrict__ src, __bf16* __restrict__ dst) {
    const size_t i = ((size_t)blockIdx.x * 256 + threadIdx.x) * 8;
    float4 a = *(const float4*)(src + i);
    float4 b = *(const float4*)(src + i + 4);
    bfx8 o = {(__bf16)a.x, (__bf16)a.y, (__bf16)a.z, (__bf16)a.w,
              (__bf16)b.x, (__bf16)b.y, (__bf16)b.z, (__bf16)b.w};
    *(bfx8*)(dst + i) = o;
}

// ------------- PW^T split-K GEMM: out[c2,c1] += sum_d A[c2,d]*B[c1,d] -------------
__global__ __launch_bounds__(256) void pwt_gemm(
    const __bf16* __restrict__ A, const __bf16* __restrict__ B,
    int Ktot, int KSPL, float* __restrict__ out, int ldo) {
    __shared__ __bf16 As[128 * 32];
    __shared__ __bf16 Bs[128 * 32];
    const int tid = threadIdx.x;
    const int lane = tid & 63, wid = tid >> 6;
    const int wr = wid >> 1, wc = wid & 1;
    const int fr = lane & 15, fq = lane >> 4;
    const int m0 = blockIdx.y * 128, n0 = blockIdx.x * 128;
    const int k0 = blockIdx.z * KSPL;

    const int flat0 = tid * 16;
    const int r0 = flat0 >> 6, c0e = (flat0 & 63) >> 1;
    const int flat1 = flat0 + 4096;
    const int r1 = flat1 >> 6, c1e = (flat1 & 63) >> 1;

    f32x4 acc[4][4] = {};

    for (int kt = k0; kt < k0 + KSPL; kt += 32) {
        __syncthreads();
        gload_lds16(A + (size_t)(m0 + r0) * Ktot + kt + c0e, (char*)As + flat0);
        gload_lds16(A + (size_t)(m0 + r1) * Ktot + kt + c1e, (char*)As + flat1);
        gload_lds16(B + (size_t)(n0 + r0) * Ktot + kt + c0e, (char*)Bs + flat0);
        gload_lds16(B + (size_t)(n0 + r1) * Ktot + kt + c1e, (char*)Bs + flat1);
        asm volatile("s_waitcnt vmcnt(0)" ::: "memory");
        __syncthreads();
        bfx8 af[4], bfv[4];
#pragma unroll
        for (int m = 0; m < 4; ++m)
            af[m] = *(const bfx8*)(As + (wr * 64 + m * 16 + fr) * 32 + fq * 8);
#pragma unroll
        for (int n = 0; n < 4; ++n)
            bfv[n] = *(const bfx8*)(Bs + (wc * 64 + n * 16 + fr) * 32 + fq * 8);
#pragma unroll
        for (int m = 0; m < 4; ++m)
#pragma unroll
            for (int n = 0; n < 4; ++n)
                acc[m][n] = __builtin_amdgcn_mfma_f32_16x16x32_bf16(
                    af[m], bfv[n], acc[m][n], 0, 0, 0);
    }
#pragma unroll
    for (int m = 0; m < 4; ++m) {
        const int grb = m0 + wr * 64 + m * 16 + fq * 4;
#pragma unroll
        for (int n = 0; n < 4; ++n) {
            const int gc = n0 + wc * 64 + n * 16 + fr;
#pragma unroll
            for (int j = 0; j < 4; ++j)
                atomicAdd(out + (size_t)(grb + j) * ldo + gc, acc[m][n][j]);
        }
    }
}

// ---------------- row softmax over C (ld CP), in place ----------------
__global__ __launch_bounds__(256) void softmax_kernel(
    __bf16* __restrict__ S, int C, int CP) {
    const int tid = threadIdx.x;
    __bf16* row = S + (size_t)blockIdx.x * CP;
    bfx4 v4 = *(const bfx4*)(row + tid * 4);
    const int base = tid * 4;
    float v[4];
    float mx = -INFINITY, rs = 0.f;
#pragma unroll
    for (int j = 0; j < 4; ++j) {
        v[j] = (float)v4[j];
        if (base + j < C) { mx = fmaxf(mx, v[j]); rs += v[j]; }
    }
    for (int o = 32; o; o >>= 1) {
        mx = fmaxf(mx, __shfl_xor(mx, o));
        rs += __shfl_xor(rs, o);
    }
    __shared__ float smx[4], srs[4], sps[4];
    if ((tid & 63) == 0) { smx[tid >> 6] = mx; srs[tid >> 6] = rs; }
    __syncthreads();
    mx = fmaxf(fmaxf(smx[0], smx[1]), fmaxf(smx[2], smx[3]));
    rs = srs[0] + srs[1] + srs[2] + srs[3];
    float p[4], ps = 0.f;
#pragma unroll
    for (int j = 0; j < 4; ++j) {
        p[j] = (base + j < C) ? exp2f((v[j] - mx) * SM_SCALE) : 0.f;
        ps += p[j];
    }
    for (int o = 32; o; o >>= 1) ps += __shfl_xor(ps, o);
    if ((tid & 63) == 0) sps[tid >> 6] = ps;
    __syncthreads();
    ps = sps[0] + sps[1] + sps[2] + sps[3];
    float inv = (rs != 0.f) ? 1.f / ps : 0.f;  // reference's nonzero mask
    bfx4 o4 = {(__bf16)(p[0] * inv), (__bf16)(p[1] * inv),
               (__bf16)(p[2] * inv), (__bf16)(p[3] * inv)};
    *(bfx4*)(row + tid * 4) = o4;
}

// ================= 256x256 8-phase NT bf16 GEMM (BK=64, 8 waves) =================
// TEMPLATE-EXACT schedule (round-9, best measured): each phase reads ITS OWN
// fragments, then BAR, lgkmcnt(0) (barrier hides ds_read drain), MFMA, BAR.
// vmcnt(6) once per tile.  Halves: H0=Ah0 H1=Bh0 H2=Ah1 H3=Bh1.
//   ph0(T): rd Ah0,Bh0(T)[12]; STG Bh1(T+1)->nbuf; LGKM(8); BAR; LGKM(0); q0; BAR
//   ph1(T): rd Bh1(T)[4];      STG Ah0(T+2)->buf;           BAR; LGKM(0); q1; BAR
//   ph2(T): rd Ah1(T)[8];      STG Bh0(T+2)->buf;           BAR; LGKM(0); q3; BAR
//   ph3(T):                    STG Ah1(T+2)->buf;           BAR;          q2;
//           VMC(6); BAR
// Ledger (2 loads/STG): at ph3(T) outstanding = 14; VMC(6) lands oldest 8 =
// ALL of T+1.  Same-buf stages issue after their target's last-reader barrier.
// MODE 4: bn0 < cpEl: B-op=B_ (Pn), out bf16 Scos; else B-op=B2 (Wb),
//         out f32 logits = auxA[gr]*acc + auxB[c].  MODE 5: logits += acc.
template <int MODE>
__global__ __launch_bounds__(512, 2) void gemm8p(
    const __bf16* __restrict__ A, const __bf16* __restrict__ B_,
    const __bf16* __restrict__ B2,
    int K, int NT, int nbxl, int nwg,
    void* __restrict__ outA, float* __restrict__ outB,
    const float* __restrict__ auxA, const float* __restrict__ auxB,
    int cpEl, int nv) {
    __shared__ __bf16 lds[65536];  // 128 KiB

    const int tid = threadIdx.x;
    const int lane = tid & 63, wid = tid >> 6;
    const int wr = wid >> 2, wc = wid & 3;
    const int fr = lane & 15, fq = lane >> 4;
    const int wr4 = wr * 4, wc2 = wc * 2;
    const int frs = fr * 32 + ((fq * 8) ^ ((fr & 8) << 1));

    // XCD-aware bijective block swizzle (nwg % 8 == 0)
    const int nbx = 1 << nbxl;
    const int lin = blockIdx.y * nbx + blockIdx.x;
    const int swz = (lin & 7) * (nwg >> 3) + (lin >> 3);
    const int bm0 = (swz >> nbxl) * 256;
    const int bn0 = (swz & (nbx - 1)) * 256;

    // staging source mapping (inverse swizzle)
    int row0, col0, row1, col1;
    {
        int Le = tid * 8;
        int st = Le >> 9, w = Le & 511;
        row0 = (st >> 1) * 16 + (w >> 5);
        col0 = (st & 1) * 32 + ((w & 31) ^ ((w >> 4) & 16));
        Le = tid * 8 + 4096;
        st = Le >> 9; w = Le & 511;
        row1 = (st >> 1) * 16 + (w >> 5);
        col1 = (st & 1) * 32 + ((w & 31) ^ ((w >> 4) & 16));
    }
    const __bf16* Ap = A + (size_t)bm0 * K;
    const __bf16* Bbase = B_;
    int bnloc = bn0;
    if (MODE == 4 && bn0 >= cpEl) { Bbase = B2; bnloc = bn0 - cpEl; }
    const __bf16* Bp = Bbase + (size_t)bnloc * K;
    const size_t hstride = (size_t)128 * K;
    const __bf16* srcA0 = Ap + (size_t)row0 * K + col0;
    const __bf16* srcA1 = Ap + (size_t)row1 * K + col1;
    const __bf16* srcB0 = Bp + (size_t)row0 * K + col0;
    const __bf16* srcB1 = Bp + (size_t)row1 * K + col1;
    const int ldsoff = tid * 8;

    // H: 0=A-h0, 1=B-h0, 2=A-h1, 3=B-h1 (compile-time); t runtime
#define STG(H, t) do {                                                         \
    const int kt_ = (t) << 6;                                                  \
    __bf16* d_ = lds + ((((t) & 1) << 14) + (((H) >> 1) << 13) +               \
                        (((H) & 1) ? 32768 : 0)) + ldsoff;                     \
    const __bf16* s0_ = (((H) & 1) ? srcB0 : srcA0) +                          \
                        (((H) >> 1) ? hstride : 0) + kt_;                      \
    const __bf16* s1_ = (((H) & 1) ? srcB1 : srcA1) +                          \
                        (((H) >> 1) ? hstride : 0) + kt_;                      \
    gload_lds16(s0_, d_);                                                      \
    gload_lds16(s1_, d_ + 4096);                                               \
} while (0)

    bfx8 fA0[4][2], fA1[4][2], fB0[2][2], fB1[2][2];
    f32x4 acc[4][4][2] = {};

#define RDA(F, H, BUFE) do {                                                   \
    _Pragma("unroll") for (int m_ = 0; m_ < 4; ++m_)                           \
      _Pragma("unroll") for (int ks_ = 0; ks_ < 2; ++ks_)                      \
        F[m_][ks_] = *(const bfx8*)&lds[(BUFE) +                               \
            (((((H) * 8) + wr4 + m_) * 2 + ks_) << 9) + frs];                  \
} while (0)
#define RDB(F, H, BUFE) do {                                                   \
    _Pragma("unroll") for (int n_ = 0; n_ < 2; ++n_)                           \
      _Pragma("unroll") for (int ks_ = 0; ks_ < 2; ++ks_)                      \
        F[n_][ks_] = *(const bfx8*)&lds[32768 + (BUFE) +                       \
            (((((H) * 8) + wc2 + n_) * 2 + ks_) << 9) + frs];                  \
} while (0)
#define MM(QI, FA, FB) do {                                                    \
    __builtin_amdgcn_s_setprio(1);                                             \
    _Pragma("unroll") for (int ks_ = 0; ks_ < 2; ++ks_)                        \
      _Pragma("unroll") for (int m_ = 0; m_ < 4; ++m_)                         \
        _Pragma("unroll") for (int n_ = 0; n_ < 2; ++n_)                       \
          acc[QI][m_][n_] = __builtin_amdgcn_mfma_f32_16x16x32_bf16(           \
              FA[m_][ks_], FB[n_][ks_], acc[QI][m_][n_], 0, 0, 0);             \
    __builtin_amdgcn_s_setprio(0);                                             \
} while (0)
#define BAR __builtin_amdgcn_s_barrier()
#define LGKM(N) asm volatile("s_waitcnt lgkmcnt(" #N ")" ::: "memory")
#define VMC(N) asm volatile("s_waitcnt vmcnt(" #N ")" ::: "memory")

    // prologue: tile0 {Ah0,Bh0,Ah1,Bh1} + tile1 {Ah0,Bh0,Ah1} = 14 loads
    STG(0, 0); STG(1, 0); STG(2, 0); STG(3, 0);
    STG(0, 1); STG(1, 1); STG(2, 1);
    VMC(6);
    BAR;

    for (int T = 0; T <= NT - 3; ++T) {
        const int bufe = (T & 1) << 14;
        // ph0: read Ah0,Bh0(T); stage Bh1(T+1)
        RDA(fA0, 0, bufe); RDB(fB0, 0, bufe); STG(3, T + 1); LGKM(8); BAR; LGKM(0);
        MM(0, fA0, fB0); BAR;
        // ph1: read Bh1(T); stage Ah0(T+2)
        RDB(fB1, 1, bufe); STG(0, T + 2); BAR; LGKM(0);
        MM(1, fA0, fB1); BAR;
        // ph2: read Ah1(T); stage Bh0(T+2)
        RDA(fA1, 1, bufe); STG(1, T + 2); BAR; LGKM(0);
        MM(3, fA1, fB1); BAR;
        // ph3: stage Ah1(T+2)
        STG(2, T + 2); BAR;
        MM(2, fA1, fB0); VMC(6); BAR;
    }
    {   // T = NT-2: stage only Bh1(NT-1); full drain at ph3
        const int T = NT - 2;
        const int bufe = (T & 1) << 14;
        RDA(fA0, 0, bufe); RDB(fB0, 0, bufe); STG(3, T + 1); LGKM(8); BAR; LGKM(0);
        MM(0, fA0, fB0); BAR;
        RDB(fB1, 1, bufe); BAR; LGKM(0);
        MM(1, fA0, fB1); BAR;
        RDA(fA1, 1, bufe); BAR; LGKM(0);
        MM(3, fA1, fB1); BAR;
        BAR;
        MM(2, fA1, fB0); VMC(0); BAR;
    }
    {   // T = NT-1: no stages, no vmcnt
        const int bufe = ((NT - 1) & 1) << 14;
        RDA(fA0, 0, bufe); RDB(fB0, 0, bufe); LGKM(8); BAR; LGKM(0);
        MM(0, fA0, fB0); BAR;
        RDB(fB1, 1, bufe); BAR; LGKM(0);
        MM(1, fA0, fB1); BAR;
        RDA(fA1, 1, bufe); BAR; LGKM(0);
        MM(3, fA1, fB1); BAR;
        MM(2, fA1, fB0);
    }
#undef STG
#undef RDA
#undef RDB
#undef MM
#undef BAR
#undef LGKM
#undef VMC

    // epilogue
#pragma unroll
    for (int q = 0; q < 4; ++q) {
        const int qm_ = q >> 1, qn_ = q & 1;
#pragma unroll
        for (int m = 0; m < 4; ++m) {
            const int grb = bm0 + qm_ * 128 + wr * 64 + m * 16 + fq * 4;
#pragma unroll
            for (int n = 0; n < 2; ++n) {
                const int gc = bn0 + qn_ * 128 + wc * 32 + n * 16 + fr;
#pragma unroll
                for (int j = 0; j < 4; ++j) {
                    const int gr = grb + j;
                    const float va = acc[q][m][n][j];
                    if (MODE == 4) {
                        if (bn0 < cpEl) {
                            ((__bf16*)outA)[(size_t)gr * cpEl + gc] = (__bf16)va;
                        } else {
                            const int c = gc - cpEl;
                            if (c < nv)
                                outB[(size_t)gr * nv + c] = auxA[gr] * va + auxB[c];
                        }
                    } else {  // MODE 5
                        if (gc < nv) {
                            float* p = outB + (size_t)gr * nv + gc;
                            *p = *p + va;
                        }
                    }
                }
            }
        }
    }
}

extern "C" void kernel_launch(void* const* d_in, const int* in_sizes, int n_in,
                              void* d_out, int out_size, void* d_ws, size_t ws_size,
                              hipStream_t stream) {
    const float* q  = (const float*)d_in[0];
    const float* pr = (const float*)d_in[1];
    const float* fw = (const float*)d_in[2];
    const float* fb = (const float*)d_in[3];
    const int C = in_sizes[3];              // 1000
    const int D = in_sizes[1] / C;          // 2048
    const int B = in_sizes[0] / D;          // 16384
    const int CP = (C + 127) & ~127;        // 1024

    float* logits = (float*)d_out;          // [B, C] f32
    float* emb = logits + (size_t)B * C;    // [B, D] f32

    char* w = (char*)d_ws;
    __bf16* Qb  = (__bf16*)w; w += (size_t)B * D * 2;     // 67.1 MB
    __bf16* Pn  = (__bf16*)w; w += (size_t)CP * D * 2;    // 4.2 MB
    __bf16* Wb  = (__bf16*)w; w += (size_t)CP * D * 2;    // 4.2 MB
    __bf16* PWT = (__bf16*)w; w += (size_t)CP * CP * 2;   // 2.1 MB
    float*  qn  = (float*)w;  w += (size_t)B * 4;         // 64 KB
    __bf16* Scos = (__bf16*)w; w += (size_t)B * CP * 2;   // 33.6 MB
    // transient aliases inside Scos (dead before bigGEMM writes Scos):
    float*  PWf = (float*)Scos;                           // CP*CP f32 = 4.2 MB
    __bf16* Pr  = Scos + (size_t)4 * 1024 * 1024;         // 4.2 MB, at +8 MB

    qnorm_kernel<<<B, 256, 0, stream>>>(q, Qb, emb, qn, D);
    pnorm_kernel<<<CP, 256, 0, stream>>>(pr, fw, Pn, Wb, Pr, PWf, C, D, CP);

    // PW^T = Wb @ Pr^T  (split-K=4, atomic f32), then cast to bf16
    pwt_gemm<<<dim3(CP / 128, CP / 128, 4), 256, 0, stream>>>(
        Wb, Pr, D, D / 4, PWf, CP);
    cast_kernel<<<(CP * CP) / 2048, 256, 0, stream>>>(PWf, PWT);

    // fused: Scos = Qb@Pn^T (bf16) | logits = qn*(Qb@Wb^T) + fb (f32)
    {
        const int nbx = 2 * CP / 256, nby = B / 256;  // 8 x 64 = 512
        gemm8p<4><<<dim3(nbx, nby), 512, 0, stream>>>(
            Qb, Pn, Wb, D, D / 64, 3, nbx * nby,
            (void*)Scos, logits, qn, fb, CP, C);
    }
    softmax_kernel<<<B, 256, 0, stream>>>(Scos, C, CP);
    // logits += attn @ PWT   (K = CP)
    {
        const int nbx = CP / 256, nby = B / 256;  // 4 x 64 = 256
        gemm8p<5><<<dim3(nbx, nby), 512, 0, stream>>>(
            Scos, PWT, nullptr, CP, CP / 64, 2, nbx * nby,
            nullptr, logits, nullptr, nullptr, CP, C);
    }
}